// Round 10
// baseline (210.954 us; speedup 1.0000x reference)
//
#include <hip/hip_runtime.h>
#include <hip/hip_bf16.h>

#define NGRAPH  64
#define TOPO_D  16
#define NBLK    512     // binning blocks (pass A); E=1.6M -> 3125 edges/block
#define MAXB    512     // LDS cap for bucket arrays (nb2 = ceil(N/256) = 391)
#define GROWS   8       // rows per wave in the register GEMM

typedef float v2f __attribute__((ext_vector_type(2)));

// exact RNE float -> bf16 pack
static __device__ __forceinline__ unsigned f2bf(float f) {
    unsigned u = __float_as_uint(f);
    return (u + 0x7FFFu + ((u >> 16) & 1u)) >> 16;
}
static __device__ __forceinline__ float bf_lo(unsigned u) { return __uint_as_float(u << 16); }
static __device__ __forceinline__ float bf_hi(unsigned u) { return __uint_as_float(u & 0xFFFF0000u); }

// ---- gemm1 body: fp32 rows x W1 -> bf16 (unscaled) -------------------------------------------
// Round-10: branch-free rows (clamped loads, store-guard only) + 4-way split accumulators.
// Old form was a 64-deep dependent FMA chain per row with an early-return branch between rows
// -> ~256+ cycle/row latency floor, no cross-row ILP. Now 8 rows x 4 chains = 32 independent
// FMA streams; s_loads pipeline across rows.
static __device__ __forceinline__ void gemm_rows_bf(
        const float* __restrict__ X, const float* Wreg,
        unsigned short* __restrict__ Abf, int row0, int N, int lane) {
    #pragma unroll
    for (int j = 0; j < GROWS; ++j) {
        int row = row0 + j;
        int rc = min(row, N - 1);          // clamp: loads are always safe, no branch
        const float* xr = X + (size_t)rc * 64;
        float a0 = 0.f, a1 = 0.f, a2 = 0.f, a3 = 0.f;
        #pragma unroll
        for (int k = 0; k < 64; k += 4) {
            a0 = fmaf(xr[k],     Wreg[k],     a0);
            a1 = fmaf(xr[k + 1], Wreg[k + 1], a1);
            a2 = fmaf(xr[k + 2], Wreg[k + 2], a2);
            a3 = fmaf(xr[k + 3], Wreg[k + 3], a3);
        }
        float acc = (a0 + a1) + (a2 + a3);
        if (row < N)
            Abf[(size_t)row * 64 + lane] = (unsigned short)f2bf(acc);
    }
}

// ---- pass A1 hybrid: [0,Gg) gemm1; [Gg,Gg+NBLK) histogram; +2 blocks: gstart, gsum=0 ---------
__global__ __launch_bounds__(256) void hybrid_gemm_hist_kernel(
        const float* __restrict__ X, const float* __restrict__ W,
        unsigned short* __restrict__ Abf,
        const int* __restrict__ dst, int* __restrict__ bhist,
        const int* __restrict__ batch, int* __restrict__ gstart,
        float* __restrict__ gsum,
        int N, int E, int Gg, int nb2, int CE) {
    __shared__ int hist[MAXB];
    int t = threadIdx.x;
    if ((int)blockIdx.x < Gg) {
        int lane = t & 63;
        float Wreg[64];
        #pragma unroll
        for (int k = 0; k < 64; ++k) Wreg[k] = W[k * 64 + lane];
        int wave = __builtin_amdgcn_readfirstlane(blockIdx.x * 4 + (t >> 6));
        gemm_rows_bf(X, Wreg, Abf, wave * GROWS, N, lane);
    } else if ((int)blockIdx.x < Gg + NBLK) {
        int blk = blockIdx.x - Gg;               // 0..NBLK-1
        for (int i = t; i < nb2; i += 256) hist[i] = 0;
        __syncthreads();
        int e0 = blk * CE, e1 = min(e0 + CE, E);
        for (int e = e0 + t; e < e1; e += 256) atomicAdd(&hist[dst[e] >> 8], 1);
        __syncthreads();
        for (int i = t; i < nb2; i += 256) bhist[blk * nb2 + i] = hist[i];
    } else if ((int)blockIdx.x == Gg + NBLK) {
        // gstart: binary search of graph boundaries in sorted batch
        int g = t;
        if (g <= NGRAPH) {
            int lo = 0, hi = N;
            while (lo < hi) {
                int mid = (lo + hi) >> 1;
                if (batch[mid] < g) lo = mid + 1; else hi = mid;
            }
            gstart[g] = lo;
        }
    } else {
        // zero pool accumulators (ws is poisoned with 0xAA every call)
        for (int i = t; i < NGRAPH * 64; i += 256) gsum[i] = 0.f;
    }
}

// ---- pass A2: exclusive scan down each bucket column of bhist (nblk=512 fixed) ---------------
__global__ __launch_bounds__(256) void scan_cols_kernel(
        int* __restrict__ bhist, int* __restrict__ ctot, int nb2) {
    __shared__ int sd[256];
    int c = blockIdx.x;
    int t = threadIdx.x;
    int v0 = bhist[t * nb2 + c];
    int v1 = bhist[(t + 256) * nb2 + c];
    int tsum = v0 + v1;
    sd[t] = tsum; __syncthreads();
    for (int off = 1; off < 256; off <<= 1) {
        int u = (t >= off) ? sd[t - off] : 0;
        __syncthreads();
        sd[t] += u;
        __syncthreads();
    }
    int excl = sd[t] - tsum;
    bhist[t * nb2 + c] = excl;
    bhist[(t + 256) * nb2 + c] = excl + v0;
    if (t == 255) ctot[c] = sd[255];
}

// ---- pass A3: scatter edges into dst-buckets; bucket bases via in-block scan of ctot ---------
__global__ __launch_bounds__(256) void scatter_sorted_kernel(
        const int* __restrict__ src, const int* __restrict__ dst,
        const int* __restrict__ bhist, const int* __restrict__ ctot,
        unsigned* __restrict__ ebuf, int E, int nb2, int CE) {
    __shared__ int sd[256];
    __shared__ int cur[MAXB];
    int blk = blockIdx.x, t = threadIdx.x;
    // in-block exclusive scan of bucket totals (2 elems/thread, scan_cols pattern)
    int v0 = (t < nb2) ? ctot[t] : 0;
    int v1 = (t + 256 < nb2) ? ctot[t + 256] : 0;
    int tsum = v0 + v1;
    sd[t] = tsum; __syncthreads();
    for (int off = 1; off < 256; off <<= 1) {
        int u = (t >= off) ? sd[t - off] : 0;
        __syncthreads();
        sd[t] += u;
        __syncthreads();
    }
    int excl = sd[t] - tsum;
    if (t < nb2)       cur[t]       = bhist[blk * nb2 + t] + excl;
    if (t + 256 < nb2) cur[t + 256] = bhist[blk * nb2 + t + 256] + excl + v0;
    __syncthreads();
    int e0 = blk * CE, e1 = min(e0 + CE, E);
    for (int e = e0 + t; e < e1; e += 256) {
        int d = dst[e];
        int pos = atomicAdd(&cur[d >> 8], 1);
        ebuf[pos] = ((unsigned)src[e] << 8) | (unsigned)(d & 255);
    }
}

// ---- pass B: per bucket: CSR col/rowptr/degi/dis + convert A bf16 -> fp8 (x dis) -------------
// Bucket base e0 = sum(ctot[0..b-1]) computed in-block (replaces cbase buffer).
__global__ __launch_bounds__(256) void build_csr_kernel(
        const unsigned* __restrict__ ebuf, const int* __restrict__ ctot,
        int* __restrict__ col, int* __restrict__ rowptr,
        int* __restrict__ degi, float* __restrict__ dis,
        const unsigned* __restrict__ Abf32, unsigned* __restrict__ A8, int N) {
    __shared__ int cnt[256];
    __shared__ int loff[256];
    __shared__ float disS[256];
    __shared__ int redS[256];
    int b = blockIdx.x, t = threadIdx.x;
    // e0 = prefix sum of ctot up to b (strided partial + tree reduce)
    int part = 0;
    for (int i = t; i < b; i += 256) part += ctot[i];
    redS[t] = part; __syncthreads();
    for (int off = 128; off > 0; off >>= 1) {
        if (t < off) redS[t] += redS[t + off];
        __syncthreads();
    }
    int e0 = redS[0];
    int e1 = e0 + ctot[b];
    cnt[t] = 0; __syncthreads();
    for (int i = e0 + t; i < e1; i += 256) atomicAdd(&cnt[ebuf[i] & 255u], 1);
    __syncthreads();
    int v = cnt[t];
    loff[t] = v; __syncthreads();
    for (int off = 1; off < 256; off <<= 1) {
        int u = (t >= off) ? loff[t - off] : 0;
        __syncthreads();
        loff[t] += u;
        __syncthreads();
    }
    int excl = loff[t] - v;
    int node = b * 256 + t;
    float ds = rsqrtf((float)v + 1.0f);
    disS[t] = ds;
    if (node < N) {
        degi[node]   = v;
        dis[node]    = ds;
        rowptr[node] = e0 + excl;
    }
    __syncthreads();
    cnt[t] = excl;              // reuse as local cursor
    __syncthreads();
    for (int i = e0 + t; i < e1; i += 256) {
        unsigned p = ebuf[i];
        int pos = atomicAdd(&cnt[p & 255u], 1);
        col[e0 + pos] = (int)(p >> 8);
    }
    // convert this bucket's A rows: bf16 * dis -> fp8 (16 dwords/row out)
    int base8 = b * 256 * 16;
    for (int i = t; i < 256 * 16; i += 256) {
        int r = i >> 4;               // row in bucket
        int dwo = i & 15;             // output dword (4 feats)
        int nd = b * 256 + r;
        if (nd < N) {
            float d2 = disS[r];
            unsigned u0 = Abf32[(size_t)nd * 32 + dwo * 2];
            unsigned u1 = Abf32[(size_t)nd * 32 + dwo * 2 + 1];
            int dw = __builtin_amdgcn_cvt_pk_fp8_f32(bf_lo(u0) * d2, bf_hi(u0) * d2, 0, false);
            dw = __builtin_amdgcn_cvt_pk_fp8_f32(bf_lo(u1) * d2, bf_hi(u1) * d2, dw, true);
            A8[base8 + i] = (unsigned)dw;
        }
    }
}

// ---- shared gather core: 8 nodes/wave, feature-sliced, fp8, acc init = self row --------------
// Proven form (round-5 best): scalar acc, unroll-8. (Round-7 lesson: unroll-16/packed regressed.)
#define CVT_ACC(vv) do { \
    v2f f0_ = __builtin_amdgcn_cvt_pk_f32_fp8((vv).x, false); acc[0] += f0_.x; acc[1] += f0_.y; \
    v2f f1_ = __builtin_amdgcn_cvt_pk_f32_fp8((vv).x, true);  acc[2] += f1_.x; acc[3] += f1_.y; \
    v2f f2_ = __builtin_amdgcn_cvt_pk_f32_fp8((vv).y, false); acc[4] += f2_.x; acc[5] += f2_.y; \
    v2f f3_ = __builtin_amdgcn_cvt_pk_f32_fp8((vv).y, true);  acc[6] += f3_.x; acc[7] += f3_.y; \
} while (0)

static __device__ __forceinline__ void gather_node(
        const unsigned* __restrict__ A8, const int* __restrict__ col,
        int beg, int deg, int node, int f8, float acc[8]) {
    const char* Abase = (const char*)A8 + f8 * 8;
    uint2 an = *(const uint2*)(Abase + ((size_t)node << 6));
    v2f a0 = __builtin_amdgcn_cvt_pk_f32_fp8(an.x, false);
    v2f a1 = __builtin_amdgcn_cvt_pk_f32_fp8(an.x, true);
    v2f a2 = __builtin_amdgcn_cvt_pk_f32_fp8(an.y, false);
    v2f a3 = __builtin_amdgcn_cvt_pk_f32_fp8(an.y, true);
    acc[0] = a0.x; acc[1] = a0.y; acc[2] = a1.x; acc[3] = a1.y;
    acc[4] = a2.x; acc[5] = a2.y; acc[6] = a3.x; acc[7] = a3.y;
    int j = 0;
    for (; j + 8 <= deg; j += 8) {               // 8 gathers in flight per lane
        int s0 = col[beg + j]     << 6;
        int s1 = col[beg + j + 1] << 6;
        int s2 = col[beg + j + 2] << 6;
        int s3 = col[beg + j + 3] << 6;
        int s4 = col[beg + j + 4] << 6;
        int s5 = col[beg + j + 5] << 6;
        int s6 = col[beg + j + 6] << 6;
        int s7 = col[beg + j + 7] << 6;
        uint2 v0 = *(const uint2*)(Abase + s0);
        uint2 v1 = *(const uint2*)(Abase + s1);
        uint2 v2 = *(const uint2*)(Abase + s2);
        uint2 v3 = *(const uint2*)(Abase + s3);
        uint2 v4 = *(const uint2*)(Abase + s4);
        uint2 v5 = *(const uint2*)(Abase + s5);
        uint2 v6 = *(const uint2*)(Abase + s6);
        uint2 v7 = *(const uint2*)(Abase + s7);
        CVT_ACC(v0); CVT_ACC(v1); CVT_ACC(v2); CVT_ACC(v3);
        CVT_ACC(v4); CVT_ACC(v5); CVT_ACC(v6); CVT_ACC(v7);
    }
    for (; j + 4 <= deg; j += 4) {               // at most one iteration
        int s0 = col[beg + j]     << 6;
        int s1 = col[beg + j + 1] << 6;
        int s2 = col[beg + j + 2] << 6;
        int s3 = col[beg + j + 3] << 6;
        uint2 v0 = *(const uint2*)(Abase + s0);
        uint2 v1 = *(const uint2*)(Abase + s1);
        uint2 v2 = *(const uint2*)(Abase + s2);
        uint2 v3 = *(const uint2*)(Abase + s3);
        CVT_ACC(v0); CVT_ACC(v1); CVT_ACC(v2); CVT_ACC(v3);
    }
    for (; j < deg; ++j) {
        int s = col[beg + j] << 6;
        uint2 v = *(const uint2*)(Abase + s);
        CVT_ACC(v);
    }
}

// ---- pull1: gather A8 -> h1 -> C8 = fp8(dis*h1), lane-local pack (NO shuffles) ---------------
// W2 is commuted past the layer-2 aggregation (segment-sum is linear), so pull1 emits the
// layer-2 gather operand directly: C = dis_src * h1. 6.4MB instead of 12.8MB Bbf.
__global__ __launch_bounds__(256) void pull_csr_kernel(
        const unsigned* __restrict__ A8, unsigned* __restrict__ C8,
        const int* __restrict__ rowptr, const int* __restrict__ degi,
        const float* __restrict__ dis, const float* __restrict__ bias,
        const int* __restrict__ col, int N) {
    int wave = (blockIdx.x * blockDim.x + threadIdx.x) >> 6;
    int lane = threadIdx.x & 63;
    int i = lane >> 3;
    int f8 = lane & 7;
    int node = wave * 8 + i;
    bool valid = node < N;
    if (!valid) node = N - 1;
    int deg = degi[node];
    int beg = rowptr[node];
    float acc[8];
    gather_node(A8, col, beg, deg, node, f8, acc);
    float d = dis[node];
    float4 b0 = ((const float4*)bias)[f8 * 2];
    float4 b1 = ((const float4*)bias)[f8 * 2 + 1];
    float r0 = fmaxf(d * acc[0] + b0.x, 0.f);
    float r1 = fmaxf(d * acc[1] + b0.y, 0.f);
    float r2 = fmaxf(d * acc[2] + b0.z, 0.f);
    float r3 = fmaxf(d * acc[3] + b0.w, 0.f);
    float r4 = fmaxf(d * acc[4] + b1.x, 0.f);
    float r5 = fmaxf(d * acc[5] + b1.y, 0.f);
    float r6 = fmaxf(d * acc[6] + b1.z, 0.f);
    float r7 = fmaxf(d * acc[7] + b1.w, 0.f);
    if (valid) {
        // each lane owns 8 CONSECUTIVE features -> fp8 pack is lane-local (build_csr pattern)
        int p0 = __builtin_amdgcn_cvt_pk_fp8_f32(d * r0, d * r1, 0, false);
        p0 = __builtin_amdgcn_cvt_pk_fp8_f32(d * r2, d * r3, p0, true);
        int p1 = __builtin_amdgcn_cvt_pk_fp8_f32(d * r4, d * r5, 0, false);
        p1 = __builtin_amdgcn_cvt_pk_fp8_f32(d * r6, d * r7, p1, true);
        uint2 o; o.x = (unsigned)p0; o.y = (unsigned)p1;
        *(uint2*)((char*)C8 + ((size_t)node << 6) + (f8 << 3)) = o;
    }
}

// ---- fused layer2: gather C8 -> s -> LDS GEMM (sxW2) -> ReLU -> mean-pool --------------------
// h2 = ReLU(dis_dst * (s . W2) + b2), s = C_self + sum_neighbors C.  512-thread blocks: the
// 16KB w2s stage is amortized over 8 waves (LDS ~37KB/block -> 4 blocks/CU -> 32-wave cap).
// LDS-staged W2 (round-6 lesson), named scalar accumulators, no shuffles (round-1/2 lesson),
// no device-scope fences (round-8 lesson).
__global__ __launch_bounds__(512) void pull2_pool_kernel(
        const unsigned* __restrict__ C8, const int* __restrict__ rowptr,
        const int* __restrict__ degi, const float* __restrict__ dis,
        const float* __restrict__ bias, const int* __restrict__ col,
        const int* __restrict__ batch, const float* __restrict__ W2,
        float* __restrict__ gsum, int N) {
    __shared__ float w2s[4096];                    // [k][f] fp32, 16KB (shared by 8 waves)
    __shared__ __align__(16) float sred[64][72];   // s vectors, padded row (288B, float4-aligned)
    __shared__ float red[8][65];
    int t = threadIdx.x;
    // stage W2 (coalesced float4; consumed after the syncthreads below)
    ((float4*)w2s)[t]       = ((const float4*)W2)[t];
    ((float4*)w2s)[t + 512] = ((const float4*)W2)[t + 512];
    int wave = (blockIdx.x * blockDim.x + t) >> 6;
    int lane = t & 63;
    int w = t >> 6;                                // 0..7
    int i = lane >> 3;
    int f8 = lane & 7;
    int node = wave * 8 + i;
    bool valid = node < N;
    if (!valid) node = N - 1;
    int deg = degi[node];
    int beg = rowptr[node];
    float acc[8];
    gather_node(C8, col, beg, deg, node, f8, acc);
    float* sp = &sred[w * 8 + i][f8 * 8];
    sp[0] = acc[0]; sp[1] = acc[1]; sp[2] = acc[2]; sp[3] = acc[3];
    sp[4] = acc[4]; sp[5] = acc[5]; sp[6] = acc[6]; sp[7] = acc[7];
    __syncthreads();
    // ---- GEMM phase: lane computes out-feature f=lane for this wave's 8 nodes ----
    float g0 = 0.f, g1 = 0.f, g2 = 0.f, g3 = 0.f, g4 = 0.f, g5 = 0.f, g6 = 0.f, g7 = 0.f;
    #pragma unroll
    for (int kc = 0; kc < 16; ++kc) {
        float wa = w2s[(kc * 4 + 0) * 64 + lane];
        float wb = w2s[(kc * 4 + 1) * 64 + lane];
        float wc = w2s[(kc * 4 + 2) * 64 + lane];
        float wd = w2s[(kc * 4 + 3) * 64 + lane];
        float4 sv;
        sv = *(const float4*)&sred[w * 8 + 0][kc * 4];
        g0 = fmaf(sv.x, wa, fmaf(sv.y, wb, fmaf(sv.z, wc, fmaf(sv.w, wd, g0))));
        sv = *(const float4*)&sred[w * 8 + 1][kc * 4];
        g1 = fmaf(sv.x, wa, fmaf(sv.y, wb, fmaf(sv.z, wc, fmaf(sv.w, wd, g1))));
        sv = *(const float4*)&sred[w * 8 + 2][kc * 4];
        g2 = fmaf(sv.x, wa, fmaf(sv.y, wb, fmaf(sv.z, wc, fmaf(sv.w, wd, g2))));
        sv = *(const float4*)&sred[w * 8 + 3][kc * 4];
        g3 = fmaf(sv.x, wa, fmaf(sv.y, wb, fmaf(sv.z, wc, fmaf(sv.w, wd, g3))));
        sv = *(const float4*)&sred[w * 8 + 4][kc * 4];
        g4 = fmaf(sv.x, wa, fmaf(sv.y, wb, fmaf(sv.z, wc, fmaf(sv.w, wd, g4))));
        sv = *(const float4*)&sred[w * 8 + 5][kc * 4];
        g5 = fmaf(sv.x, wa, fmaf(sv.y, wb, fmaf(sv.z, wc, fmaf(sv.w, wd, g5))));
        sv = *(const float4*)&sred[w * 8 + 6][kc * 4];
        g6 = fmaf(sv.x, wa, fmaf(sv.y, wb, fmaf(sv.z, wc, fmaf(sv.w, wd, g6))));
        sv = *(const float4*)&sred[w * 8 + 7][kc * 4];
        g7 = fmaf(sv.x, wa, fmaf(sv.y, wb, fmaf(sv.z, wc, fmaf(sv.w, wd, g7))));
    }
    // ---- epilogue: ReLU(dis*g + b2), then pool ----
    int base = (blockIdx.x * 8 + w) * 8;           // first node of this wave
    float d0 = dis[min(base + 0, N - 1)];
    float d1 = dis[min(base + 1, N - 1)];
    float d2 = dis[min(base + 2, N - 1)];
    float d3 = dis[min(base + 3, N - 1)];
    float d4 = dis[min(base + 4, N - 1)];
    float d5 = dis[min(base + 5, N - 1)];
    float d6 = dis[min(base + 6, N - 1)];
    float d7 = dis[min(base + 7, N - 1)];
    float bf = bias[lane];
    float h0 = fmaxf(fmaf(d0, g0, bf), 0.f);
    float h1 = fmaxf(fmaf(d1, g1, bf), 0.f);
    float h2 = fmaxf(fmaf(d2, g2, bf), 0.f);
    float h3 = fmaxf(fmaf(d3, g3, bf), 0.f);
    float h4 = fmaxf(fmaf(d4, g4, bf), 0.f);
    float h5 = fmaxf(fmaf(d5, g5, bf), 0.f);
    float h6 = fmaxf(fmaf(d6, g6, bf), 0.f);
    float h7 = fmaxf(fmaf(d7, g7, bf), 0.f);
    if (base + 0 >= N) h0 = 0.f;
    if (base + 1 >= N) h1 = 0.f;
    if (base + 2 >= N) h2 = 0.f;
    if (base + 3 >= N) h3 = 0.f;
    if (base + 4 >= N) h4 = 0.f;
    if (base + 5 >= N) h5 = 0.f;
    if (base + 6 >= N) h6 = 0.f;
    if (base + 7 >= N) h7 = 0.f;
    int nodeA = blockIdx.x * 64;
    int gA = batch[min(nodeA, N - 1)];             // block-uniform -> scalar
    int gB = batch[min(nodeA + 63, N - 1)];
    if (gA == gB) {
        // whole block in one graph (common: batch sorted): lane-local 8-sum + LDS reduce
        red[w][lane] = h0 + h1 + h2 + h3 + h4 + h5 + h6 + h7;
        __syncthreads();
        if (t < 64) {
            float s = red[0][t] + red[1][t] + red[2][t] + red[3][t]
                    + red[4][t] + red[5][t] + red[6][t] + red[7][t];
            unsafeAtomicAdd(&gsum[gA * 64 + t], s);
        }
    } else {
        // graph boundary inside block (rare): per-node atomics (uniform control flow)
        int q0 = batch[min(base + 0, N - 1)]; unsafeAtomicAdd(&gsum[q0 * 64 + lane], h0);
        int q1 = batch[min(base + 1, N - 1)]; unsafeAtomicAdd(&gsum[q1 * 64 + lane], h1);
        int q2 = batch[min(base + 2, N - 1)]; unsafeAtomicAdd(&gsum[q2 * 64 + lane], h2);
        int q3 = batch[min(base + 3, N - 1)]; unsafeAtomicAdd(&gsum[q3 * 64 + lane], h3);
        int q4 = batch[min(base + 4, N - 1)]; unsafeAtomicAdd(&gsum[q4 * 64 + lane], h4);
        int q5 = batch[min(base + 5, N - 1)]; unsafeAtomicAdd(&gsum[q5 * 64 + lane], h5);
        int q6 = batch[min(base + 6, N - 1)]; unsafeAtomicAdd(&gsum[q6 * 64 + lane], h6);
        int q7 = batch[min(base + 7, N - 1)]; unsafeAtomicAdd(&gsum[q7 * 64 + lane], h7);
    }
}

// ---- head: counts derived from gstart --------------------------------------------------------
__global__ __launch_bounds__(256) void head_kernel(
        const float* __restrict__ gsum, const int* __restrict__ gstart,
        const float* __restrict__ topo, const float* __restrict__ Wlin,
        const float* __restrict__ blin, float* __restrict__ out) {
    int t = threadIdx.x;              // 256 = 64 graphs x 4 classes
    int g = t >> 2;
    int c = t & 3;
    float cntf = (float)(gstart[g + 1] - gstart[g]);
    float inv = 1.0f / fmaxf(cntf, 1.0f);
    float v = blin[c];
    #pragma unroll
    for (int f = 0; f < 64; ++f) v += gsum[g * 64 + f] * inv * Wlin[f * 4 + c];
    #pragma unroll
    for (int t2 = 0; t2 < TOPO_D; ++t2) v += topo[g * TOPO_D + t2] * Wlin[(64 + t2) * 4 + c];
    out[g * 4 + c] = v;
}

extern "C" void kernel_launch(void* const* d_in, const int* in_sizes, int n_in,
                              void* d_out, int out_size, void* d_ws, size_t ws_size,
                              hipStream_t stream) {
    const float* x     = (const float*)d_in[0];
    const int*   ei    = (const int*)d_in[1];
    const int*   batch = (const int*)d_in[2];
    const float* topo  = (const float*)d_in[3];
    const float* W1    = (const float*)d_in[4];
    const float* b1    = (const float*)d_in[5];
    const float* W2    = (const float*)d_in[6];
    const float* b2    = (const float*)d_in[7];
    const float* Wlin  = (const float*)d_in[8];
    const float* blin  = (const float*)d_in[9];
    float* out = (float*)d_out;

    const int N = in_sizes[0] / 64;      // 100000
    const int E = in_sizes[1] / 2;       // 1600000
    const int* src = ei;
    const int* dst = ei + E;
    const int nb2 = (N + 255) / 256;     // 391 dst-buckets of 256 nodes
    const int CE  = (E + NBLK - 1) / NBLK;

    // workspace layout (bytes)
    char* ws = (char*)d_ws;
    size_t off = 0;
    unsigned short* Abf = (unsigned short*)(ws + off); off += (size_t)N * 64 * 2;   // 12.8 MB (gemm1 bf16)
    unsigned* A8     = (unsigned*)(ws + off); off += (size_t)N * 64;                // 6.4 MB (layer-1 fp8)
    unsigned* C8     = (unsigned*)(ws + off); off += (size_t)N * 64;                // 6.4 MB (layer-2 fp8: dis*h1)
    int*      col    = (int*)     (ws + off); off += (size_t)E * 4;                 // 6.4 MB
    unsigned* ebuf   = (unsigned*)(ws + off); off += (size_t)E * 4;                 // 6.4 MB
    int*      bhist  = (int*)     (ws + off); off += (size_t)NBLK * nb2 * 4;        // 0.8 MB
    int*      ctot   = (int*)     (ws + off); off += (size_t)(nb2 + 8) * 4;
    int*      rowptr = (int*)     (ws + off); off += (size_t)(N + 1) * 4;
    int*      degi   = (int*)     (ws + off); off += (size_t)N * 4;
    float*    dis    = (float*)   (ws + off); off += (size_t)N * 4;
    int*      gstart = (int*)     (ws + off); off += (size_t)(NGRAPH + 8) * 4;
    float*    gsum   = (float*)   (ws + off); off += (size_t)NGRAPH * 64 * 4;

    // ---- build: (gemm1 | histogram | gstart | gsum=0) -> column scan -> scatter -> CSR -------
    const int nWaves = (N + GROWS - 1) / GROWS;  // 12500
    const int Gg = (nWaves + 3) / 4;             // 3125 gemm blocks
    hybrid_gemm_hist_kernel<<<Gg + NBLK + 2, 256, 0, stream>>>(
        x, W1, Abf, dst, bhist, batch, gstart, gsum, N, E, Gg, nb2, CE);
    scan_cols_kernel<<<nb2, 256, 0, stream>>>(bhist, ctot, nb2);
    scatter_sorted_kernel<<<NBLK, 256, 0, stream>>>(src, dst, bhist, ctot, ebuf, E, nb2, CE);
    build_csr_kernel<<<nb2, 256, 0, stream>>>(ebuf, ctot, col, rowptr, degi, dis,
                                              (const unsigned*)Abf, A8, N);

    // ---- layer 1 pull (fp8 gather) -> C8 = fp8(dis*h1)  [gemm2 commuted into pull2] ----
    int pullBlocks = ((N + 7) / 8 + 3) / 4;      // 3125
    pull_csr_kernel<<<pullBlocks, 256, 0, stream>>>(A8, C8, rowptr, degi, dis, b1, col, N);

    // ---- layer 2: fused gather + LDS GEMM + mean-pool (512-thread blocks) ----
    int pull2Blocks = (N + 63) / 64;             // 1563
    pull2_pool_kernel<<<pull2Blocks, 512, 0, stream>>>(C8, rowptr, degi, dis, b2, col,
                                                       batch, W2, gsum, N);

    // ---- head ----
    head_kernel<<<1, 256, 0, stream>>>(gsum, gstart, topo, Wlin, blin, out);
}

// Round 11
// 208.391 us; speedup vs baseline: 1.0123x; 1.0123x over previous
//
#include <hip/hip_runtime.h>
#include <hip/hip_bf16.h>

#define NGRAPH  64
#define TOPO_D  16
#define NBLK    512     // binning blocks (pass A); E=1.6M -> 3125 edges/block
#define MAXB    512     // LDS cap for bucket arrays (nb2 = ceil(N/256) = 391)
#define GROWS   8       // rows per wave in the register GEMM

typedef float v2f __attribute__((ext_vector_type(2)));

// exact RNE float -> bf16 pack
static __device__ __forceinline__ unsigned f2bf(float f) {
    unsigned u = __float_as_uint(f);
    return (u + 0x7FFFu + ((u >> 16) & 1u)) >> 16;
}
static __device__ __forceinline__ float bf_lo(unsigned u) { return __uint_as_float(u << 16); }
static __device__ __forceinline__ float bf_hi(unsigned u) { return __uint_as_float(u & 0xFFFF0000u); }

// ---- gemm1 body: fp32 rows x W1 -> bf16 (unscaled) -------------------------------------------
// Branch-free rows (clamped loads, store-guard only) + 4-way split accumulators.
static __device__ __forceinline__ void gemm_rows_bf(
        const float* __restrict__ X, const float* Wreg,
        unsigned short* __restrict__ Abf, int row0, int N, int lane) {
    #pragma unroll
    for (int j = 0; j < GROWS; ++j) {
        int row = row0 + j;
        int rc = min(row, N - 1);          // clamp: loads are always safe, no branch
        const float* xr = X + (size_t)rc * 64;
        float a0 = 0.f, a1 = 0.f, a2 = 0.f, a3 = 0.f;
        #pragma unroll
        for (int k = 0; k < 64; k += 4) {
            a0 = fmaf(xr[k],     Wreg[k],     a0);
            a1 = fmaf(xr[k + 1], Wreg[k + 1], a1);
            a2 = fmaf(xr[k + 2], Wreg[k + 2], a2);
            a3 = fmaf(xr[k + 3], Wreg[k + 3], a3);
        }
        float acc = (a0 + a1) + (a2 + a3);
        if (row < N)
            Abf[(size_t)row * 64 + lane] = (unsigned short)f2bf(acc);
    }
}

// gemm1 as a per-block job: block-level gemm index gb covers rows [gb*32, gb*32+32).
// Round-11: gemm1's 3125 blocks ride along in the hist/scan/scatter kernels (its output Abf
// is first consumed by build_csr), filling the machine during latency-bound build stages.
static __device__ __forceinline__ void gemm1_block(
        const float* __restrict__ X, const float* __restrict__ W,
        unsigned short* __restrict__ Abf, int gb, int N, int t) {
    int lane = t & 63;
    float Wreg[64];
    #pragma unroll
    for (int k = 0; k < 64; ++k) Wreg[k] = W[k * 64 + lane];
    int wave = __builtin_amdgcn_readfirstlane(gb * 4 + (t >> 6));
    gemm_rows_bf(X, Wreg, Abf, wave * GROWS, N, lane);
}

// ---- pass A1: [0,GA) gemm1 part A; [GA,GA+NBLK) histogram; +2 blocks: gstart, gsum=0 ---------
__global__ __launch_bounds__(256) void hist_gemm_kernel(
        const float* __restrict__ X, const float* __restrict__ W,
        unsigned short* __restrict__ Abf,
        const int* __restrict__ dst, int* __restrict__ bhist,
        const int* __restrict__ batch, int* __restrict__ gstart,
        float* __restrict__ gsum,
        int N, int E, int GA, int nb2, int CE) {
    __shared__ int hist[MAXB];
    int t = threadIdx.x;
    if ((int)blockIdx.x < GA) {
        gemm1_block(X, W, Abf, blockIdx.x, N, t);
    } else if ((int)blockIdx.x < GA + NBLK) {
        int blk = blockIdx.x - GA;               // 0..NBLK-1
        for (int i = t; i < nb2; i += 256) hist[i] = 0;
        __syncthreads();
        int e0 = blk * CE, e1 = min(e0 + CE, E);
        for (int e = e0 + t; e < e1; e += 256) atomicAdd(&hist[dst[e] >> 8], 1);
        __syncthreads();
        for (int i = t; i < nb2; i += 256) bhist[blk * nb2 + i] = hist[i];
    } else if ((int)blockIdx.x == GA + NBLK) {
        // gstart: binary search of graph boundaries in sorted batch
        int g = t;
        if (g <= NGRAPH) {
            int lo = 0, hi = N;
            while (lo < hi) {
                int mid = (lo + hi) >> 1;
                if (batch[mid] < g) lo = mid + 1; else hi = mid;
            }
            gstart[g] = lo;
        }
    } else {
        // zero pool accumulators (ws is poisoned with 0xAA every call)
        for (int i = t; i < NGRAPH * 64; i += 256) gsum[i] = 0.f;
    }
}

// ---- pass A2: [0,nb2) column scan of bhist; [nb2,nb2+GB) gemm1 part B ------------------------
__global__ __launch_bounds__(256) void scan_gemm_kernel(
        int* __restrict__ bhist, int* __restrict__ ctot,
        const float* __restrict__ X, const float* __restrict__ W,
        unsigned short* __restrict__ Abf,
        int N, int GA, int nb2) {
    __shared__ int sd[256];
    int t = threadIdx.x;
    if ((int)blockIdx.x >= nb2) {
        gemm1_block(X, W, Abf, (int)blockIdx.x - nb2 + GA, N, t);
        return;
    }
    int c = blockIdx.x;
    int v0 = bhist[t * nb2 + c];
    int v1 = bhist[(t + 256) * nb2 + c];
    int tsum = v0 + v1;
    sd[t] = tsum; __syncthreads();
    for (int off = 1; off < 256; off <<= 1) {
        int u = (t >= off) ? sd[t - off] : 0;
        __syncthreads();
        sd[t] += u;
        __syncthreads();
    }
    int excl = sd[t] - tsum;
    bhist[t * nb2 + c] = excl;
    bhist[(t + 256) * nb2 + c] = excl + v0;
    if (t == 255) ctot[c] = sd[255];
}

// ---- pass A3: [0,NBLK) scatter into dst-buckets; [NBLK,NBLK+GC) gemm1 part C -----------------
__global__ __launch_bounds__(256) void scatter_gemm_kernel(
        const int* __restrict__ src, const int* __restrict__ dst,
        const int* __restrict__ bhist, const int* __restrict__ ctot,
        unsigned* __restrict__ ebuf,
        const float* __restrict__ X, const float* __restrict__ W,
        unsigned short* __restrict__ Abf,
        int N, int E, int GAB, int nb2, int CE) {
    __shared__ int sd[256];
    __shared__ int cur[MAXB];
    int t = threadIdx.x;
    if ((int)blockIdx.x >= NBLK) {
        gemm1_block(X, W, Abf, (int)blockIdx.x - NBLK + GAB, N, t);
        return;
    }
    int blk = blockIdx.x;
    // in-block exclusive scan of bucket totals (2 elems/thread, scan_cols pattern)
    int v0 = (t < nb2) ? ctot[t] : 0;
    int v1 = (t + 256 < nb2) ? ctot[t + 256] : 0;
    int tsum = v0 + v1;
    sd[t] = tsum; __syncthreads();
    for (int off = 1; off < 256; off <<= 1) {
        int u = (t >= off) ? sd[t - off] : 0;
        __syncthreads();
        sd[t] += u;
        __syncthreads();
    }
    int excl = sd[t] - tsum;
    if (t < nb2)       cur[t]       = bhist[blk * nb2 + t] + excl;
    if (t + 256 < nb2) cur[t + 256] = bhist[blk * nb2 + t + 256] + excl + v0;
    __syncthreads();
    int e0 = blk * CE, e1 = min(e0 + CE, E);
    for (int e = e0 + t; e < e1; e += 256) {
        int d = dst[e];
        int pos = atomicAdd(&cur[d >> 8], 1);
        ebuf[pos] = ((unsigned)src[e] << 8) | (unsigned)(d & 255);
    }
}

// ---- pass B: per bucket: CSR col/rowptr/degi/dis + convert A bf16 -> fp8 (x dis) -------------
// Bucket base e0 = sum(ctot[0..b-1]) computed in-block (replaces cbase buffer).
__global__ __launch_bounds__(256) void build_csr_kernel(
        const unsigned* __restrict__ ebuf, const int* __restrict__ ctot,
        int* __restrict__ col, int* __restrict__ rowptr,
        int* __restrict__ degi, float* __restrict__ dis,
        const unsigned* __restrict__ Abf32, unsigned* __restrict__ A8, int N) {
    __shared__ int cnt[256];
    __shared__ int loff[256];
    __shared__ float disS[256];
    __shared__ int redS[256];
    int b = blockIdx.x, t = threadIdx.x;
    // e0 = prefix sum of ctot up to b (strided partial + tree reduce)
    int part = 0;
    for (int i = t; i < b; i += 256) part += ctot[i];
    redS[t] = part; __syncthreads();
    for (int off = 128; off > 0; off >>= 1) {
        if (t < off) redS[t] += redS[t + off];
        __syncthreads();
    }
    int e0 = redS[0];
    int e1 = e0 + ctot[b];
    cnt[t] = 0; __syncthreads();
    for (int i = e0 + t; i < e1; i += 256) atomicAdd(&cnt[ebuf[i] & 255u], 1);
    __syncthreads();
    int v = cnt[t];
    loff[t] = v; __syncthreads();
    for (int off = 1; off < 256; off <<= 1) {
        int u = (t >= off) ? loff[t - off] : 0;
        __syncthreads();
        loff[t] += u;
        __syncthreads();
    }
    int excl = loff[t] - v;
    int node = b * 256 + t;
    float ds = rsqrtf((float)v + 1.0f);
    disS[t] = ds;
    if (node < N) {
        degi[node]   = v;
        dis[node]    = ds;
        rowptr[node] = e0 + excl;
    }
    __syncthreads();
    cnt[t] = excl;              // reuse as local cursor
    __syncthreads();
    for (int i = e0 + t; i < e1; i += 256) {
        unsigned p = ebuf[i];
        int pos = atomicAdd(&cnt[p & 255u], 1);
        col[e0 + pos] = (int)(p >> 8);
    }
    // convert this bucket's A rows: bf16 * dis -> fp8 (16 dwords/row out)
    int base8 = b * 256 * 16;
    for (int i = t; i < 256 * 16; i += 256) {
        int r = i >> 4;               // row in bucket
        int dwo = i & 15;             // output dword (4 feats)
        int nd = b * 256 + r;
        if (nd < N) {
            float d2 = disS[r];
            unsigned u0 = Abf32[(size_t)nd * 32 + dwo * 2];
            unsigned u1 = Abf32[(size_t)nd * 32 + dwo * 2 + 1];
            int dw = __builtin_amdgcn_cvt_pk_fp8_f32(bf_lo(u0) * d2, bf_hi(u0) * d2, 0, false);
            dw = __builtin_amdgcn_cvt_pk_fp8_f32(bf_lo(u1) * d2, bf_hi(u1) * d2, dw, true);
            A8[base8 + i] = (unsigned)dw;
        }
    }
}

// ---- shared gather core: 8 nodes/wave, feature-sliced, fp8, acc init = self row --------------
// Proven form (round-5 best): scalar acc, unroll-8. (Round-7 lesson: unroll-16/packed regressed.)
#define CVT_ACC(vv) do { \
    v2f f0_ = __builtin_amdgcn_cvt_pk_f32_fp8((vv).x, false); acc[0] += f0_.x; acc[1] += f0_.y; \
    v2f f1_ = __builtin_amdgcn_cvt_pk_f32_fp8((vv).x, true);  acc[2] += f1_.x; acc[3] += f1_.y; \
    v2f f2_ = __builtin_amdgcn_cvt_pk_f32_fp8((vv).y, false); acc[4] += f2_.x; acc[5] += f2_.y; \
    v2f f3_ = __builtin_amdgcn_cvt_pk_f32_fp8((vv).y, true);  acc[6] += f3_.x; acc[7] += f3_.y; \
} while (0)

static __device__ __forceinline__ void gather_node(
        const unsigned* __restrict__ A8, const int* __restrict__ col,
        int beg, int deg, int node, int f8, float acc[8]) {
    const char* Abase = (const char*)A8 + f8 * 8;
    uint2 an = *(const uint2*)(Abase + ((size_t)node << 6));
    v2f a0 = __builtin_amdgcn_cvt_pk_f32_fp8(an.x, false);
    v2f a1 = __builtin_amdgcn_cvt_pk_f32_fp8(an.x, true);
    v2f a2 = __builtin_amdgcn_cvt_pk_f32_fp8(an.y, false);
    v2f a3 = __builtin_amdgcn_cvt_pk_f32_fp8(an.y, true);
    acc[0] = a0.x; acc[1] = a0.y; acc[2] = a1.x; acc[3] = a1.y;
    acc[4] = a2.x; acc[5] = a2.y; acc[6] = a3.x; acc[7] = a3.y;
    int j = 0;
    for (; j + 8 <= deg; j += 8) {               // 8 gathers in flight per lane
        int s0 = col[beg + j]     << 6;
        int s1 = col[beg + j + 1] << 6;
        int s2 = col[beg + j + 2] << 6;
        int s3 = col[beg + j + 3] << 6;
        int s4 = col[beg + j + 4] << 6;
        int s5 = col[beg + j + 5] << 6;
        int s6 = col[beg + j + 6] << 6;
        int s7 = col[beg + j + 7] << 6;
        uint2 v0 = *(const uint2*)(Abase + s0);
        uint2 v1 = *(const uint2*)(Abase + s1);
        uint2 v2 = *(const uint2*)(Abase + s2);
        uint2 v3 = *(const uint2*)(Abase + s3);
        uint2 v4 = *(const uint2*)(Abase + s4);
        uint2 v5 = *(const uint2*)(Abase + s5);
        uint2 v6 = *(const uint2*)(Abase + s6);
        uint2 v7 = *(const uint2*)(Abase + s7);
        CVT_ACC(v0); CVT_ACC(v1); CVT_ACC(v2); CVT_ACC(v3);
        CVT_ACC(v4); CVT_ACC(v5); CVT_ACC(v6); CVT_ACC(v7);
    }
    for (; j + 4 <= deg; j += 4) {               // at most one iteration
        int s0 = col[beg + j]     << 6;
        int s1 = col[beg + j + 1] << 6;
        int s2 = col[beg + j + 2] << 6;
        int s3 = col[beg + j + 3] << 6;
        uint2 v0 = *(const uint2*)(Abase + s0);
        uint2 v1 = *(const uint2*)(Abase + s1);
        uint2 v2 = *(const uint2*)(Abase + s2);
        uint2 v3 = *(const uint2*)(Abase + s3);
        CVT_ACC(v0); CVT_ACC(v1); CVT_ACC(v2); CVT_ACC(v3);
    }
    for (; j < deg; ++j) {
        int s = col[beg + j] << 6;
        uint2 v = *(const uint2*)(Abase + s);
        CVT_ACC(v);
    }
}

// ---- pull1: gather A8 -> h1 -> C8 = fp8(dis*h1), lane-local pack (NO shuffles) ---------------
// W2 is commuted past the layer-2 aggregation (segment-sum is linear), so pull1 emits the
// layer-2 gather operand directly: C = dis_src * h1. 6.4MB instead of 12.8MB Bbf.
__global__ __launch_bounds__(256) void pull_csr_kernel(
        const unsigned* __restrict__ A8, unsigned* __restrict__ C8,
        const int* __restrict__ rowptr, const int* __restrict__ degi,
        const float* __restrict__ dis, const float* __restrict__ bias,
        const int* __restrict__ col, int N) {
    int wave = (blockIdx.x * blockDim.x + threadIdx.x) >> 6;
    int lane = threadIdx.x & 63;
    int i = lane >> 3;
    int f8 = lane & 7;
    int node = wave * 8 + i;
    bool valid = node < N;
    if (!valid) node = N - 1;
    int deg = degi[node];
    int beg = rowptr[node];
    float acc[8];
    gather_node(A8, col, beg, deg, node, f8, acc);
    float d = dis[node];
    float4 b0 = ((const float4*)bias)[f8 * 2];
    float4 b1 = ((const float4*)bias)[f8 * 2 + 1];
    float r0 = fmaxf(d * acc[0] + b0.x, 0.f);
    float r1 = fmaxf(d * acc[1] + b0.y, 0.f);
    float r2 = fmaxf(d * acc[2] + b0.z, 0.f);
    float r3 = fmaxf(d * acc[3] + b0.w, 0.f);
    float r4 = fmaxf(d * acc[4] + b1.x, 0.f);
    float r5 = fmaxf(d * acc[5] + b1.y, 0.f);
    float r6 = fmaxf(d * acc[6] + b1.z, 0.f);
    float r7 = fmaxf(d * acc[7] + b1.w, 0.f);
    if (valid) {
        // each lane owns 8 CONSECUTIVE features -> fp8 pack is lane-local (build_csr pattern)
        int p0 = __builtin_amdgcn_cvt_pk_fp8_f32(d * r0, d * r1, 0, false);
        p0 = __builtin_amdgcn_cvt_pk_fp8_f32(d * r2, d * r3, p0, true);
        int p1 = __builtin_amdgcn_cvt_pk_fp8_f32(d * r4, d * r5, 0, false);
        p1 = __builtin_amdgcn_cvt_pk_fp8_f32(d * r6, d * r7, p1, true);
        uint2 o; o.x = (unsigned)p0; o.y = (unsigned)p1;
        *(uint2*)((char*)C8 + ((size_t)node << 6) + (f8 << 3)) = o;
    }
}

// ---- fused layer2: gather C8 -> s -> LDS GEMM (sxW2) -> ReLU -> mean-pool --------------------
// h2 = ReLU(dis_dst * (s . W2) + b2), s = C_self + sum_neighbors C.  512-thread blocks: the
// 16KB w2s stage is amortized over 8 waves (LDS ~37KB/block -> 4 blocks/CU -> 32-wave cap).
// LDS-staged W2 (round-6 lesson), named scalar accumulators, no shuffles (round-1/2 lesson),
// no device-scope fences (round-8 lesson).
__global__ __launch_bounds__(512) void pull2_pool_kernel(
        const unsigned* __restrict__ C8, const int* __restrict__ rowptr,
        const int* __restrict__ degi, const float* __restrict__ dis,
        const float* __restrict__ bias, const int* __restrict__ col,
        const int* __restrict__ batch, const float* __restrict__ W2,
        float* __restrict__ gsum, int N) {
    __shared__ float w2s[4096];                    // [k][f] fp32, 16KB (shared by 8 waves)
    __shared__ __align__(16) float sred[64][72];   // s vectors, padded row (288B, float4-aligned)
    __shared__ float red[8][65];
    int t = threadIdx.x;
    // stage W2 (coalesced float4; consumed after the syncthreads below)
    ((float4*)w2s)[t]       = ((const float4*)W2)[t];
    ((float4*)w2s)[t + 512] = ((const float4*)W2)[t + 512];
    int wave = (blockIdx.x * blockDim.x + t) >> 6;
    int lane = t & 63;
    int w = t >> 6;                                // 0..7
    int i = lane >> 3;
    int f8 = lane & 7;
    int node = wave * 8 + i;
    bool valid = node < N;
    if (!valid) node = N - 1;
    int deg = degi[node];
    int beg = rowptr[node];
    float acc[8];
    gather_node(C8, col, beg, deg, node, f8, acc);
    float* sp = &sred[w * 8 + i][f8 * 8];
    sp[0] = acc[0]; sp[1] = acc[1]; sp[2] = acc[2]; sp[3] = acc[3];
    sp[4] = acc[4]; sp[5] = acc[5]; sp[6] = acc[6]; sp[7] = acc[7];
    __syncthreads();
    // ---- GEMM phase: lane computes out-feature f=lane for this wave's 8 nodes ----
    float g0 = 0.f, g1 = 0.f, g2 = 0.f, g3 = 0.f, g4 = 0.f, g5 = 0.f, g6 = 0.f, g7 = 0.f;
    #pragma unroll
    for (int kc = 0; kc < 16; ++kc) {
        float wa = w2s[(kc * 4 + 0) * 64 + lane];
        float wb = w2s[(kc * 4 + 1) * 64 + lane];
        float wc = w2s[(kc * 4 + 2) * 64 + lane];
        float wd = w2s[(kc * 4 + 3) * 64 + lane];
        float4 sv;
        sv = *(const float4*)&sred[w * 8 + 0][kc * 4];
        g0 = fmaf(sv.x, wa, fmaf(sv.y, wb, fmaf(sv.z, wc, fmaf(sv.w, wd, g0))));
        sv = *(const float4*)&sred[w * 8 + 1][kc * 4];
        g1 = fmaf(sv.x, wa, fmaf(sv.y, wb, fmaf(sv.z, wc, fmaf(sv.w, wd, g1))));
        sv = *(const float4*)&sred[w * 8 + 2][kc * 4];
        g2 = fmaf(sv.x, wa, fmaf(sv.y, wb, fmaf(sv.z, wc, fmaf(sv.w, wd, g2))));
        sv = *(const float4*)&sred[w * 8 + 3][kc * 4];
        g3 = fmaf(sv.x, wa, fmaf(sv.y, wb, fmaf(sv.z, wc, fmaf(sv.w, wd, g3))));
        sv = *(const float4*)&sred[w * 8 + 4][kc * 4];
        g4 = fmaf(sv.x, wa, fmaf(sv.y, wb, fmaf(sv.z, wc, fmaf(sv.w, wd, g4))));
        sv = *(const float4*)&sred[w * 8 + 5][kc * 4];
        g5 = fmaf(sv.x, wa, fmaf(sv.y, wb, fmaf(sv.z, wc, fmaf(sv.w, wd, g5))));
        sv = *(const float4*)&sred[w * 8 + 6][kc * 4];
        g6 = fmaf(sv.x, wa, fmaf(sv.y, wb, fmaf(sv.z, wc, fmaf(sv.w, wd, g6))));
        sv = *(const float4*)&sred[w * 8 + 7][kc * 4];
        g7 = fmaf(sv.x, wa, fmaf(sv.y, wb, fmaf(sv.z, wc, fmaf(sv.w, wd, g7))));
    }
    // ---- epilogue: ReLU(dis*g + b2), then pool ----
    int base = (blockIdx.x * 8 + w) * 8;           // first node of this wave
    float d0 = dis[min(base + 0, N - 1)];
    float d1 = dis[min(base + 1, N - 1)];
    float d2 = dis[min(base + 2, N - 1)];
    float d3 = dis[min(base + 3, N - 1)];
    float d4 = dis[min(base + 4, N - 1)];
    float d5 = dis[min(base + 5, N - 1)];
    float d6 = dis[min(base + 6, N - 1)];
    float d7 = dis[min(base + 7, N - 1)];
    float bf = bias[lane];
    float h0 = fmaxf(fmaf(d0, g0, bf), 0.f);
    float h1 = fmaxf(fmaf(d1, g1, bf), 0.f);
    float h2 = fmaxf(fmaf(d2, g2, bf), 0.f);
    float h3 = fmaxf(fmaf(d3, g3, bf), 0.f);
    float h4 = fmaxf(fmaf(d4, g4, bf), 0.f);
    float h5 = fmaxf(fmaf(d5, g5, bf), 0.f);
    float h6 = fmaxf(fmaf(d6, g6, bf), 0.f);
    float h7 = fmaxf(fmaf(d7, g7, bf), 0.f);
    if (base + 0 >= N) h0 = 0.f;
    if (base + 1 >= N) h1 = 0.f;
    if (base + 2 >= N) h2 = 0.f;
    if (base + 3 >= N) h3 = 0.f;
    if (base + 4 >= N) h4 = 0.f;
    if (base + 5 >= N) h5 = 0.f;
    if (base + 6 >= N) h6 = 0.f;
    if (base + 7 >= N) h7 = 0.f;
    int nodeA = blockIdx.x * 64;
    int gA = batch[min(nodeA, N - 1)];             // block-uniform -> scalar
    int gB = batch[min(nodeA + 63, N - 1)];
    if (gA == gB) {
        // whole block in one graph (common: batch sorted): lane-local 8-sum + LDS reduce
        red[w][lane] = h0 + h1 + h2 + h3 + h4 + h5 + h6 + h7;
        __syncthreads();
        if (t < 64) {
            float s = red[0][t] + red[1][t] + red[2][t] + red[3][t]
                    + red[4][t] + red[5][t] + red[6][t] + red[7][t];
            unsafeAtomicAdd(&gsum[gA * 64 + t], s);
        }
    } else {
        // graph boundary inside block (rare): per-node atomics (uniform control flow)
        int q0 = batch[min(base + 0, N - 1)]; unsafeAtomicAdd(&gsum[q0 * 64 + lane], h0);
        int q1 = batch[min(base + 1, N - 1)]; unsafeAtomicAdd(&gsum[q1 * 64 + lane], h1);
        int q2 = batch[min(base + 2, N - 1)]; unsafeAtomicAdd(&gsum[q2 * 64 + lane], h2);
        int q3 = batch[min(base + 3, N - 1)]; unsafeAtomicAdd(&gsum[q3 * 64 + lane], h3);
        int q4 = batch[min(base + 4, N - 1)]; unsafeAtomicAdd(&gsum[q4 * 64 + lane], h4);
        int q5 = batch[min(base + 5, N - 1)]; unsafeAtomicAdd(&gsum[q5 * 64 + lane], h5);
        int q6 = batch[min(base + 6, N - 1)]; unsafeAtomicAdd(&gsum[q6 * 64 + lane], h6);
        int q7 = batch[min(base + 7, N - 1)]; unsafeAtomicAdd(&gsum[q7 * 64 + lane], h7);
    }
}

// ---- head: counts derived from gstart --------------------------------------------------------
__global__ __launch_bounds__(256) void head_kernel(
        const float* __restrict__ gsum, const int* __restrict__ gstart,
        const float* __restrict__ topo, const float* __restrict__ Wlin,
        const float* __restrict__ blin, float* __restrict__ out) {
    int t = threadIdx.x;              // 256 = 64 graphs x 4 classes
    int g = t >> 2;
    int c = t & 3;
    float cntf = (float)(gstart[g + 1] - gstart[g]);
    float inv = 1.0f / fmaxf(cntf, 1.0f);
    float v = blin[c];
    #pragma unroll
    for (int f = 0; f < 64; ++f) v += gsum[g * 64 + f] * inv * Wlin[f * 4 + c];
    #pragma unroll
    for (int t2 = 0; t2 < TOPO_D; ++t2) v += topo[g * TOPO_D + t2] * Wlin[(64 + t2) * 4 + c];
    out[g * 4 + c] = v;
}

extern "C" void kernel_launch(void* const* d_in, const int* in_sizes, int n_in,
                              void* d_out, int out_size, void* d_ws, size_t ws_size,
                              hipStream_t stream) {
    const float* x     = (const float*)d_in[0];
    const int*   ei    = (const int*)d_in[1];
    const int*   batch = (const int*)d_in[2];
    const float* topo  = (const float*)d_in[3];
    const float* W1    = (const float*)d_in[4];
    const float* b1    = (const float*)d_in[5];
    const float* W2    = (const float*)d_in[6];
    const float* b2    = (const float*)d_in[7];
    const float* Wlin  = (const float*)d_in[8];
    const float* blin  = (const float*)d_in[9];
    float* out = (float*)d_out;

    const int N = in_sizes[0] / 64;      // 100000
    const int E = in_sizes[1] / 2;       // 1600000
    const int* src = ei;
    const int* dst = ei + E;
    const int nb2 = (N + 255) / 256;     // 391 dst-buckets of 256 nodes
    const int CE  = (E + NBLK - 1) / NBLK;

    // workspace layout (bytes)
    char* ws = (char*)d_ws;
    size_t off = 0;
    unsigned short* Abf = (unsigned short*)(ws + off); off += (size_t)N * 64 * 2;   // 12.8 MB (gemm1 bf16)
    unsigned* A8     = (unsigned*)(ws + off); off += (size_t)N * 64;                // 6.4 MB (layer-1 fp8)
    unsigned* C8     = (unsigned*)(ws + off); off += (size_t)N * 64;                // 6.4 MB (layer-2 fp8: dis*h1)
    int*      col    = (int*)     (ws + off); off += (size_t)E * 4;                 // 6.4 MB
    unsigned* ebuf   = (unsigned*)(ws + off); off += (size_t)E * 4;                 // 6.4 MB
    int*      bhist  = (int*)     (ws + off); off += (size_t)NBLK * nb2 * 4;        // 0.8 MB
    int*      ctot   = (int*)     (ws + off); off += (size_t)(nb2 + 8) * 4;
    int*      rowptr = (int*)     (ws + off); off += (size_t)(N + 1) * 4;
    int*      degi   = (int*)     (ws + off); off += (size_t)N * 4;
    float*    dis    = (float*)   (ws + off); off += (size_t)N * 4;
    int*      gstart = (int*)     (ws + off); off += (size_t)(NGRAPH + 8) * 4;
    float*    gsum   = (float*)   (ws + off); off += (size_t)NGRAPH * 64 * 4;

    // ---- build: gemm1 split 3 ways across (hist | scan | scatter) to fill idle stages -------
    const int nWaves = (N + GROWS - 1) / GROWS;  // 12500
    const int Gg = (nWaves + 3) / 4;             // 3125 gemm blocks total
    const int GA = (Gg + 2) / 3;                 // 1042 in hist kernel
    const int GB = GA;                           // 1042 in scan kernel
    const int GC = Gg - GA - GB;                 // 1041 in scatter kernel
    hist_gemm_kernel<<<GA + NBLK + 2, 256, 0, stream>>>(
        x, W1, Abf, dst, bhist, batch, gstart, gsum, N, E, GA, nb2, CE);
    scan_gemm_kernel<<<nb2 + GB, 256, 0, stream>>>(bhist, ctot, x, W1, Abf, N, GA, nb2);
    scatter_gemm_kernel<<<NBLK + GC, 256, 0, stream>>>(src, dst, bhist, ctot, ebuf,
                                                       x, W1, Abf, N, E, GA + GB, nb2, CE);
    build_csr_kernel<<<nb2, 256, 0, stream>>>(ebuf, ctot, col, rowptr, degi, dis,
                                              (const unsigned*)Abf, A8, N);

    // ---- layer 1 pull (fp8 gather) -> C8 = fp8(dis*h1)  [gemm2 commuted into pull2] ----
    int pullBlocks = ((N + 7) / 8 + 3) / 4;      // 3125
    pull_csr_kernel<<<pullBlocks, 256, 0, stream>>>(A8, C8, rowptr, degi, dis, b1, col, N);

    // ---- layer 2: fused gather + LDS GEMM + mean-pool (512-thread blocks) ----
    int pull2Blocks = (N + 63) / 64;             // 1563
    pull2_pool_kernel<<<pull2Blocks, 512, 0, stream>>>(C8, rowptr, degi, dis, b2, col,
                                                       batch, W2, gsum, N);

    // ---- head ----
    head_kernel<<<1, 256, 0, stream>>>(gsum, gstart, topo, Wlin, blin, out);
}